// Round 5
// baseline (361.461 us; speedup 1.0000x reference)
//
#include <hip/hip_runtime.h>
#include <stdint.h>

#define DIN 256
#define DOUT 64
#define LMAX 50
#define NEG_INF -1e9f
#define WSTRIDE 264   // bf16 elems per row in LDS (padded: 2-way bank alias, free)

typedef short bf16x8 __attribute__((ext_vector_type(8)));
typedef float f32x4  __attribute__((ext_vector_type(4)));

static __device__ __forceinline__ unsigned short f2bf(float x) {
    unsigned int u = __float_as_uint(x);
    u += 0x7fffu + ((u >> 16) & 1u);     // RNE
    return (unsigned short)(u >> 16);
}
static __device__ __forceinline__ float bflo(unsigned int u) { return __uint_as_float(u << 16); }
static __device__ __forceinline__ float bfhi(unsigned int u) { return __uint_as_float(u & 0xffff0000u); }

// ---------------------------------------------------------------------------
// Kernel 1: projection via bf16 MFMA 16x16x32 (UNCHANGED from round 4 —
// A staged through LDS once, coalesced; ~40-45 us vs 37 us HBM floor).
// ---------------------------------------------------------------------------
__global__ __launch_bounds__(256) void proj_kernel(
    const float* __restrict__ embed, const float* __restrict__ W,
    unsigned short* __restrict__ ep16, int N)
{
    __shared__ unsigned short wl[64 * WSTRIDE];   // 33,792 B
    __shared__ unsigned short al[64 * WSTRIDE];   // 33,792 B

    const int tid  = threadIdx.x;
    const int lane = tid & 63;
    const int wv   = tid >> 6;
    const int mrow = lane & 15;
    const int quad = lane >> 4;
    const int m_base = blockIdx.x * 64;

    // ---- stage W: fp32 -> bf16, layout wl[n*264 + k], coalesced ----
#pragma unroll
    for (int i = 0; i < 16; ++i) {
        const int idx4 = tid + 256 * i;          // float4 index
        const int e    = idx4 * 4;               // element = n*256 + k
        const int n    = e >> 8;
        const int k    = e & 255;
        const float4 f = *(const float4*)&W[e];
        union { unsigned short s[4]; unsigned long long v; } p;
        p.s[0] = f2bf(f.x); p.s[1] = f2bf(f.y);
        p.s[2] = f2bf(f.z); p.s[3] = f2bf(f.w);
        *(unsigned long long*)&wl[n * WSTRIDE + k] = p.v;
    }
    // ---- stage A tile: rows m_base..m_base+63, each element read ONCE ----
#pragma unroll
    for (int i = 0; i < 16; ++i) {
        const int idx4 = tid + 256 * i;
        const int e    = idx4 * 4;
        const int n    = e >> 8;                 // 0..63 tile row
        const int k    = e & 255;
        int row = m_base + n;
        if (row >= N) row = N - 1;               // clamp; store-guarded
        const float4 f = *(const float4*)&embed[(size_t)row * DIN + k];
        union { unsigned short s[4]; unsigned long long v; } p;
        p.s[0] = f2bf(f.x); p.s[1] = f2bf(f.y);
        p.s[2] = f2bf(f.z); p.s[3] = f2bf(f.w);
        *(unsigned long long*)&al[n * WSTRIDE + k] = p.v;
    }
    __syncthreads();

    // wave wv owns rows m_base + wv*16 .. +15
    f32x4 acc[4];
#pragma unroll
    for (int nt = 0; nt < 4; ++nt) acc[nt] = (f32x4){0.f, 0.f, 0.f, 0.f};

#pragma unroll
    for (int kc = 0; kc < DIN; kc += 32) {
        const bf16x8 afrag =
            *(const bf16x8*)&al[(wv * 16 + mrow) * WSTRIDE + kc + quad * 8];
#pragma unroll
        for (int nt = 0; nt < 4; ++nt) {
            const bf16x8 bfrag =
                *(const bf16x8*)&wl[(nt * 16 + mrow) * WSTRIDE + kc + quad * 8];
            acc[nt] = __builtin_amdgcn_mfma_f32_16x16x32_bf16(
                afrag, bfrag, acc[nt], 0, 0, 0);
        }
    }

#pragma unroll
    for (int nt = 0; nt < 4; ++nt)
#pragma unroll
        for (int r = 0; r < 4; ++r) {
            const int row = m_base + wv * 16 + quad * 4 + r;
            if (row < N)
                ep16[(size_t)row * DOUT + nt * 16 + mrow] = f2bf(acc[nt][r]);
        }
}

// ---------------------------------------------------------------------------
// Kernel 2: GAT attention + aggregation.
// NEW this round: 2 nodes per wave, counted-vmcnt pipeline (T3/T4 pattern).
//  * FIXED 7 DMA instructions per node (6 x w16 + 1 x w4, uncompacted —
//    invalid rows refetch n0, L2-hot; R3 proved trip count is free) so the
//    vmcnt immediates are exact: issue A(7), issue B(7), vmcnt(7) -> A
//    ready (B still in flight), compute A, vmcnt(1) -> FIFO retires all of
//    B's older DMAs (the 1 = A's out-store), compute B. B's entire gather
//    latency hides under A's compute; exposed drains per node halve; wave
//    count halves.
//  * neighbor ids via __shfl from registers (no chained address loads);
//    both fronts loaded before any DMA so no compiler-inserted vmcnt(0)
//    can drain the pipeline.
//  * LDS 51,200 B -> 3 blocks/CU (12 waves); __launch_bounds__(256,3).
//  * phase 2 now has a compile-time trip count (7) -> fully unrolled.
// ---------------------------------------------------------------------------
__global__ __launch_bounds__(256, 3) void agg_kernel(
    const int* __restrict__ neighs, const void* __restrict__ mask,
    const unsigned int* __restrict__ ep16u,
    const float* __restrict__ a_src,
    float* __restrict__ out, int B)
{
    __shared__ unsigned int fwbuf[4][2][LMAX * 32];   // 51,200 B -> 3 blocks/CU

    const int tid  = threadIdx.x;
    const int lane = tid & 63;
    const int wv   = tid >> 6;
    const int nodeA = blockIdx.x * 8 + wv * 2;
    const int nodeB = nodeA + 1;
    const int cA = nodeA < B ? nodeA : B - 1;      // clamp (grid exact for B=50000)
    const int cB = nodeB < B ? nodeB : B - 1;

    // mask storage-format detection: flat element 50 (row1,col0) always True.
    const unsigned int* mw = (const unsigned int*)mask;
    const bool byteMode = (mw[12] > 1u);

    // ---- both fronts loaded BEFORE any DMA (keeps vmcnt counts exact) ----
    bool mvA = false, mvB = false;
    int  nbA = 0, nbB = 0;
    if (lane < LMAX) {
        const int miA = cA * LMAX + lane;
        const int miB = cB * LMAX + lane;
        if (byteMode) {
            mvA = ((const uint8_t*)mask)[miA] != 0;
            mvB = ((const uint8_t*)mask)[miB] != 0;
        } else {
            mvA = ((const int*)mask)[miA] != 0;
            mvB = ((const int*)mask)[miB] != 0;
        }
        nbA = neighs[miA];
        nbB = neighs[miB];
    }
    const unsigned long long vmA = __ballot(mvA);
    const unsigned long long vmB = __ballot(mvB);

    unsigned int* bufA = fwbuf[wv][0];
    unsigned int* bufB = fwbuf[wv][1];

    const int sub    = lane >> 3;                  // 0..7 = row&7 in w16 groups
    const int gchunk = (lane & 7) ^ sub;           // chunk-XOR-rotated layout
    const int r2     = 48 + (lane >> 5);           // w4 tail rows 48,49
    const int w32    = lane & 31;
    const int gwd2   = (((w32 >> 2) ^ (r2 & 7)) << 2) + (w32 & 3);

    // 7 DMA instructions, always — fixed count for the vmcnt immediates.
#define ISSUE_NODE(bufX, vmX, nbX)                                             \
    {                                                                          \
        const int n0 = __shfl(nbX, 0, 64);                                     \
        _Pragma("unroll")                                                      \
        for (int i = 0; i < 6; ++i) {                                          \
            const int r = 8 * i + sub;                                         \
            int n = __shfl(nbX, r, 64);                                        \
            n = ((vmX >> r) & 1ull) ? n : n0;                                  \
            const unsigned int* gp = ep16u + (size_t)n * 32 + gchunk * 4;      \
            __builtin_amdgcn_global_load_lds(                                  \
                (const __attribute__((address_space(1))) void*)gp,             \
                (__attribute__((address_space(3))) void*)&bufX[i * 256],       \
                16, 0, 0);                                                     \
        }                                                                      \
        int n = __shfl(nbX, r2, 64);                                           \
        n = ((vmX >> r2) & 1ull) ? n : n0;                                     \
        const unsigned int* gp = ep16u + (size_t)n * 32 + gwd2;                \
        __builtin_amdgcn_global_load_lds(                                      \
            (const __attribute__((address_space(1))) void*)gp,                 \
            (__attribute__((address_space(3))) void*)&bufX[48 * 32], 4, 0, 0); \
    }

    ISSUE_NODE(bufA, vmA, nbA)                     // 7 outstanding
    ISSUE_NODE(bufB, vmB, nbB)                     // 14 outstanding

    auto compute = [&](const unsigned int* buf, unsigned long long vmX, int node,
                       int nodeRaw) {
        // ---- phase 1: per-lane row dot with a_src (uniform k-octets) ----
        const int lc   = lane < LMAX ? lane : 0;   // slot 0 always valid
        const int rot7 = lc & 7;
        const unsigned int* fr = buf + lc * 32;
        float dot = 0.f;
#pragma unroll
        for (int k8 = 0; k8 < 8; ++k8) {
            const uint4 u = *(const uint4*)&fr[((k8 ^ rot7) << 2)];
            dot = fmaf(bflo(u.x), a_src[k8 * 8 + 0], dot);
            dot = fmaf(bfhi(u.x), a_src[k8 * 8 + 1], dot);
            dot = fmaf(bflo(u.y), a_src[k8 * 8 + 2], dot);
            dot = fmaf(bfhi(u.y), a_src[k8 * 8 + 3], dot);
            dot = fmaf(bflo(u.z), a_src[k8 * 8 + 4], dot);
            dot = fmaf(bfhi(u.z), a_src[k8 * 8 + 5], dot);
            dot = fmaf(bflo(u.w), a_src[k8 * 8 + 6], dot);
            dot = fmaf(bfhi(u.w), a_src[k8 * 8 + 7], dot);
        }
        const float lr = dot >= 0.f ? dot : 0.2f * dot;
        const bool valid = (lane < LMAX) && ((vmX >> lane) & 1ull);
        float s = valid ? lr : NEG_INF;

        float mx = s;
#pragma unroll
        for (int m = 32; m >= 1; m >>= 1) mx = fmaxf(mx, __shfl_xor(mx, m, 64));
        const float e = __expf(s - mx);            // invalid lanes -> exactly 0
        float se = e;
#pragma unroll
        for (int m = 32; m >= 1; m >>= 1) se += __shfl_xor(se, m, 64);
        const float attn = e / se;                 // lane r holds weight w_r

        // ---- phase 2: 7 fixed iters, b128 chunk-per-lane ----
        const int s8 = lane >> 3;
        const int gc = lane & 7;
        float acc[8];
#pragma unroll
        for (int j = 0; j < 8; ++j) acc[j] = 0.f;
#pragma unroll
        for (int i = 0; i < 7; ++i) {
            const int r  = 8 * i + s8;             // up to 55
            const int rr = r < LMAX ? r : LMAX - 1;  // clamp (w=0 beyond; avoid
                                                     // 0*NaN from uninit LDS)
            const float w = __shfl(attn, r, 64);   // lanes >= 50 hold 0
            const uint4 u = *(const uint4*)&buf[rr * 32 + ((gc ^ (rr & 7)) << 2)];
            acc[0] = fmaf(w, bflo(u.x), acc[0]);
            acc[1] = fmaf(w, bfhi(u.x), acc[1]);
            acc[2] = fmaf(w, bflo(u.y), acc[2]);
            acc[3] = fmaf(w, bfhi(u.y), acc[3]);
            acc[4] = fmaf(w, bflo(u.z), acc[4]);
            acc[5] = fmaf(w, bfhi(u.z), acc[5]);
            acc[6] = fmaf(w, bflo(u.w), acc[6]);
            acc[7] = fmaf(w, bfhi(u.w), acc[7]);
        }
#pragma unroll
        for (int m = 8; m <= 32; m <<= 1)
#pragma unroll
            for (int j = 0; j < 8; ++j) acc[j] += __shfl_xor(acc[j], m, 64);

        if (nodeRaw < B && lane < 8) {
            float* op = out + (size_t)node * DOUT + 8 * lane;
            float4 o0; o0.x = acc[0]; o0.y = acc[1]; o0.z = acc[2]; o0.w = acc[3];
            float4 o1; o1.x = acc[4]; o1.y = acc[5]; o1.z = acc[6]; o1.w = acc[7];
            *(float4*)op       = o0;
            *(float4*)(op + 4) = o1;
        }
    };

    // A ready: 14 outstanding -> wait until <= 7 (FIFO: A's 7 retired).
    asm volatile("s_waitcnt vmcnt(7)" ::: "memory");
    __builtin_amdgcn_sched_barrier(0);
    compute(bufA, vmA, cA, nodeA);

    // B ready: allow 1 outstanding (A's out-store, newer than B's DMAs).
    asm volatile("s_waitcnt vmcnt(1)" ::: "memory");
    __builtin_amdgcn_sched_barrier(0);
    compute(bufB, vmB, cB, nodeB);
#undef ISSUE_NODE
}

// ---------------------------------------------------------------------------
extern "C" void kernel_launch(void* const* d_in, const int* in_sizes, int n_in,
                              void* d_out, int out_size, void* d_ws, size_t ws_size,
                              hipStream_t stream)
{
    const int*   neighs  = (const int*)d_in[0];
    const void*  mask    = d_in[1];
    const float* embed   = (const float*)d_in[3];
    const float* W       = (const float*)d_in[4];
    const float* a_src   = (const float*)d_in[5];
    float* out = (float*)d_out;

    const int B = in_sizes[2];            // 50000
    const int N = in_sizes[3] / DIN;      // 200000

    unsigned short* ep16 = (unsigned short*)d_ws;   // N*64*2 = 25.6 MB

    proj_kernel<<<dim3((N + 63) / 64), dim3(256), 0, stream>>>(embed, W, ep16, N);
    agg_kernel<<<dim3((B + 7) / 8), dim3(256), 0, stream>>>(
        neighs, mask, (const unsigned int*)ep16, a_src, out, B);
}

// Round 6
// 350.153 us; speedup vs baseline: 1.0323x; 1.0323x over previous
//
#include <hip/hip_runtime.h>
#include <stdint.h>

#define DIN 256
#define DOUT 64
#define LMAX 50
#define NEG_INF -1e9f
#define WSTRIDE 264   // bf16 elems per row in LDS (padded: 2-way bank alias, free)

typedef short bf16x8 __attribute__((ext_vector_type(8)));
typedef float f32x4  __attribute__((ext_vector_type(4)));

static __device__ __forceinline__ unsigned short f2bf(float x) {
    unsigned int u = __float_as_uint(x);
    u += 0x7fffu + ((u >> 16) & 1u);     // RNE
    return (unsigned short)(u >> 16);
}
static __device__ __forceinline__ float bflo(unsigned int u) { return __uint_as_float(u << 16); }
static __device__ __forceinline__ float bfhi(unsigned int u) { return __uint_as_float(u & 0xffff0000u); }

// ---------------------------------------------------------------------------
// Kernel 1: projection via bf16 MFMA 16x16x32.
// NEW this round: PERSISTENT grid (512 blocks = 2/CU, the LDS-limited
// residency). W is staged+converted ONCE per block instead of once per tile
// (was 3125x: 200 MB of redundant L2 reads + ~160 redundant VALU convert
// instrs/thread/block). Grid-strides over the 3125 64-row A-tiles; the
// A-staging, MFMA loop, and epilogue are byte-identical to round 4.
// ---------------------------------------------------------------------------
__global__ __launch_bounds__(256) void proj_kernel(
    const float* __restrict__ embed, const float* __restrict__ W,
    unsigned short* __restrict__ ep16, int N, int ntiles)
{
    __shared__ unsigned short wl[64 * WSTRIDE];   // 33,792 B
    __shared__ unsigned short al[64 * WSTRIDE];   // 33,792 B  (67.6 KB -> 2 blocks/CU)

    const int tid  = threadIdx.x;
    const int lane = tid & 63;
    const int wv   = tid >> 6;
    const int mrow = lane & 15;
    const int quad = lane >> 4;

    // ---- stage W once: fp32 -> bf16, layout wl[n*264 + k], coalesced ----
#pragma unroll
    for (int i = 0; i < 16; ++i) {
        const int idx4 = tid + 256 * i;          // float4 index
        const int e    = idx4 * 4;               // element = n*256 + k
        const int n    = e >> 8;
        const int k    = e & 255;
        const float4 f = *(const float4*)&W[e];
        union { unsigned short s[4]; unsigned long long v; } p;
        p.s[0] = f2bf(f.x); p.s[1] = f2bf(f.y);
        p.s[2] = f2bf(f.z); p.s[3] = f2bf(f.w);
        *(unsigned long long*)&wl[n * WSTRIDE + k] = p.v;
    }
    __syncthreads();                              // wl ready

    for (int tile = blockIdx.x; tile < ntiles; tile += gridDim.x) {
        const int m_base = tile * 64;

        // ---- stage A tile: rows m_base..+63, each element read ONCE ----
#pragma unroll
        for (int i = 0; i < 16; ++i) {
            const int idx4 = tid + 256 * i;
            const int e    = idx4 * 4;
            const int n    = e >> 8;             // 0..63 tile row
            const int k    = e & 255;
            int row = m_base + n;
            if (row >= N) row = N - 1;           // clamp; store-guarded
            const float4 f = *(const float4*)&embed[(size_t)row * DIN + k];
            union { unsigned short s[4]; unsigned long long v; } p;
            p.s[0] = f2bf(f.x); p.s[1] = f2bf(f.y);
            p.s[2] = f2bf(f.z); p.s[3] = f2bf(f.w);
            *(unsigned long long*)&al[n * WSTRIDE + k] = p.v;
        }
        __syncthreads();                          // al ready

        // wave wv owns rows m_base + wv*16 .. +15
        f32x4 acc[4];
#pragma unroll
        for (int nt = 0; nt < 4; ++nt) acc[nt] = (f32x4){0.f, 0.f, 0.f, 0.f};

#pragma unroll
        for (int kc = 0; kc < DIN; kc += 32) {
            const bf16x8 afrag =
                *(const bf16x8*)&al[(wv * 16 + mrow) * WSTRIDE + kc + quad * 8];
#pragma unroll
            for (int nt = 0; nt < 4; ++nt) {
                const bf16x8 bfrag =
                    *(const bf16x8*)&wl[(nt * 16 + mrow) * WSTRIDE + kc + quad * 8];
                acc[nt] = __builtin_amdgcn_mfma_f32_16x16x32_bf16(
                    afrag, bfrag, acc[nt], 0, 0, 0);
            }
        }

#pragma unroll
        for (int nt = 0; nt < 4; ++nt)
#pragma unroll
            for (int r = 0; r < 4; ++r) {
                const int row = m_base + wv * 16 + quad * 4 + r;
                if (row < N)
                    ep16[(size_t)row * DOUT + nt * 16 + mrow] = f2bf(acc[nt][r]);
            }
        __syncthreads();                          // protect al before next stage
    }
}

// ---------------------------------------------------------------------------
// Kernel 2: GAT attention + aggregation. EXACT REVERT to round 4 (the proven
// best: 1 node/wave, compacted gather, 25.6 KB LDS -> 6 blocks/CU = 24
// waves/CU). R5 proved agg is TLP-latency-bound: the 2-node counted-vmcnt
// pipeline halved occupancy and cost +12 us. 24 waves/CU is within 1 of the
// LDS ceiling (160 KB / 6.4 KB-per-wave-buffer = 25).
// ---------------------------------------------------------------------------
__global__ __launch_bounds__(256, 6) void agg_kernel(
    const int* __restrict__ neighs, const void* __restrict__ mask,
    const unsigned int* __restrict__ ep16u,
    const float* __restrict__ a_src,
    float* __restrict__ out, int B)
{
    __shared__ unsigned int fwbuf[4][LMAX * 32];   // 25,600 B -> 6 blocks/CU

    const int tid  = threadIdx.x;
    const int lane = tid & 63;
    const int wv   = tid >> 6;
    const int b    = blockIdx.x * 4 + wv;
    const int bc   = b < B ? b : B - 1;            // clamp (grid exact for B=50000)

    // mask storage-format detection: flat element 50 (row1,col0) always True.
    const unsigned int* mw = (const unsigned int*)mask;
    const bool byteMode = (mw[12] > 1u);

    // per-lane neighbor mask (lane = l) + neighbor id
    const int* nb = neighs + (size_t)bc * LMAX;
    bool mvalid = false;
    int  nbv    = 0;
    if (lane < LMAX) {
        const int mi = bc * LMAX + lane;
        mvalid = byteMode ? (((const uint8_t*)mask)[mi] != 0)
                          : (((const int*)mask)[mi] != 0);
        nbv = nb[lane];
    }
    const unsigned long long vm = __ballot(mvalid);
    const int nv = (int)__popcll(vm);              // >= 1 (mask[:,0] always True)

    // ---- register compaction via ds_permute push ----
    const int p    = (int)__popcll(vm & ((1ull << lane) - 1ull));
    const int dsta = mvalid ? p : (nv + (lane - p));
    const int cnb  = __builtin_amdgcn_ds_permute(dsta << 2, nbv);
    // lane r (r < nv) now holds the r-th valid neighbor id in a register.

    // ---- async gather of compacted rows, chunk-XOR-rotated layout ----
    unsigned int* buf = fwbuf[wv];
    const int sub    = lane >> 3;                  // 0..7 = slot&7 in full groups
    const int gchunk = (lane & 7) ^ sub;
    const int f      = nv >> 3;                    // full 8-row groups (uniform)
    for (int i = 0; i < f; ++i) {
        const int r = 8 * i + sub;                 // r < nv guaranteed
        const int n = __shfl(cnb, r, 64);
        const unsigned int* gp = ep16u + (size_t)n * 32 + gchunk * 4;
        __builtin_amdgcn_global_load_lds(
            (const __attribute__((address_space(1))) void*)gp,
            (__attribute__((address_space(3))) void*)&buf[i * 256],
            16, 0, 0);
    }
    // tail: width-4 pairs (2 rows / instr), slots stay <= 50
    const int t     = nv & 7;
    const int npair = (t + 1) >> 1;                // uniform, 0..4
    const int rbase = 8 * f;
    for (int p2 = 0; p2 < npair; ++p2) {
        const int r   = rbase + 2 * p2 + (lane >> 5);
        const int rc  = r < nv ? r : nv - 1;       // duplicate-fill odd tail slot
        const int n   = __shfl(cnb, rc, 64);
        const int w   = lane & 31;
        const int gwd = (((w >> 2) ^ (r & 7)) << 2) + (w & 3);
        const unsigned int* gp = ep16u + (size_t)n * 32 + gwd;
        __builtin_amdgcn_global_load_lds(
            (const __attribute__((address_space(1))) void*)gp,
            (__attribute__((address_space(3))) void*)&buf[(rbase + 2 * p2) * 32],
            4, 0, 0);
    }

    // per-wave DMA drain only — buffers are wave-private, no block barrier
    asm volatile("s_waitcnt vmcnt(0)" ::: "memory");

    // ---- phase 1: uniform k-octets, bank-uniform b128, a_src in SGPRs ----
    const int lc   = lane < nv ? lane : nv - 1;    // clamp: read a valid row
    const int rot7 = lc & 7;
    const unsigned int* fr = buf + lc * 32;
    float dot = 0.f;
#pragma unroll
    for (int k8 = 0; k8 < 8; ++k8) {
        const uint4 u = *(const uint4*)&fr[((k8 ^ rot7) << 2)];
        dot = fmaf(bflo(u.x), a_src[k8 * 8 + 0], dot);
        dot = fmaf(bfhi(u.x), a_src[k8 * 8 + 1], dot);
        dot = fmaf(bflo(u.y), a_src[k8 * 8 + 2], dot);
        dot = fmaf(bfhi(u.y), a_src[k8 * 8 + 3], dot);
        dot = fmaf(bflo(u.z), a_src[k8 * 8 + 4], dot);
        dot = fmaf(bfhi(u.z), a_src[k8 * 8 + 5], dot);
        dot = fmaf(bflo(u.w), a_src[k8 * 8 + 6], dot);
        dot = fmaf(bfhi(u.w), a_src[k8 * 8 + 7], dot);
    }
    const float lr = dot >= 0.f ? dot : 0.2f * dot;
    float s = (lane < nv) ? lr : NEG_INF;

    float mx = s;
#pragma unroll
    for (int m = 32; m >= 1; m >>= 1) mx = fmaxf(mx, __shfl_xor(mx, m, 64));
    const float e = __expf(s - mx);                // lanes >= nv -> exactly 0
    float se = e;
#pragma unroll
    for (int m = 32; m >= 1; m >>= 1) se += __shfl_xor(se, m, 64);
    const float attn = e / se;                     // lane r holds weight w_r

    // ---- phase 2: 8 rows/iter, b128 chunk-per-lane, pipelined ----
    const int s8   = lane >> 3;                    // row sub-slot 0..7
    const int gc   = lane & 7;                     // fixed col-octet (cols 8gc..+7)
    const int nit8 = (nv + 7) >> 3;                // 1..7

    float acc[8];
#pragma unroll
    for (int j = 0; j < 8; ++j) acc[j] = 0.f;

    // prefetch iteration 0
    int  rr0 = s8 < nv ? s8 : nv - 1;              // clamp (init'd slots only)
    uint4 u  = *(const uint4*)&buf[rr0 * 32 + ((gc ^ (rr0 & 7)) << 2)];
    float w  = __shfl(attn, s8, 64);               // lanes r>=nv hold attn==0

    for (int i = 0; i < nit8; ++i) {
        const int inx = (i + 1 < nit8) ? i + 1 : i;    // last iter: harmless re-read
        const int r   = 8 * inx + s8;
        const int rr  = r < nv ? r : nv - 1;
        const uint4 un = *(const uint4*)&buf[rr * 32 + ((gc ^ (rr & 7)) << 2)];
        const float wn = __shfl(attn, r, 64);          // r <= 55 < 64
        acc[0] = fmaf(w, bflo(u.x), acc[0]);
        acc[1] = fmaf(w, bfhi(u.x), acc[1]);
        acc[2] = fmaf(w, bflo(u.y), acc[2]);
        acc[3] = fmaf(w, bfhi(u.y), acc[3]);
        acc[4] = fmaf(w, bflo(u.z), acc[4]);
        acc[5] = fmaf(w, bfhi(u.z), acc[5]);
        acc[6] = fmaf(w, bflo(u.w), acc[6]);
        acc[7] = fmaf(w, bfhi(u.w), acc[7]);
        u = un; w = wn;
    }

    // reduce over the 8 lanes sharing a col-octet (lane bits 3..5)
#pragma unroll
    for (int m = 8; m <= 32; m <<= 1)
#pragma unroll
        for (int j = 0; j < 8; ++j) acc[j] += __shfl_xor(acc[j], m, 64);

    if (b < B && lane < 8) {
        float* op = out + (size_t)b * DOUT + 8 * lane;
        float4 o0; o0.x = acc[0]; o0.y = acc[1]; o0.z = acc[2]; o0.w = acc[3];
        float4 o1; o1.x = acc[4]; o1.y = acc[5]; o1.z = acc[6]; o1.w = acc[7];
        *(float4*)op       = o0;
        *(float4*)(op + 4) = o1;
    }
}

// ---------------------------------------------------------------------------
extern "C" void kernel_launch(void* const* d_in, const int* in_sizes, int n_in,
                              void* d_out, int out_size, void* d_ws, size_t ws_size,
                              hipStream_t stream)
{
    const int*   neighs  = (const int*)d_in[0];
    const void*  mask    = d_in[1];
    const float* embed   = (const float*)d_in[3];
    const float* W       = (const float*)d_in[4];
    const float* a_src   = (const float*)d_in[5];
    float* out = (float*)d_out;

    const int B = in_sizes[2];            // 50000
    const int N = in_sizes[3] / DIN;      // 200000

    unsigned short* ep16 = (unsigned short*)d_ws;   // N*64*2 = 25.6 MB

    const int ntiles = (N + 63) / 64;     // 3125
    const int pgrid  = ntiles < 512 ? ntiles : 512; // 2 blocks/CU, persistent

    proj_kernel<<<dim3(pgrid), dim3(256), 0, stream>>>(embed, W, ep16, N, ntiles);
    agg_kernel<<<dim3((B + 3) / 4), dim3(256), 0, stream>>>(
        neighs, mask, (const unsigned int*)ep16, a_src, out, B);
}